// Round 1
// baseline (2500.591 us; speedup 1.0000x reference)
//
#include <hip/hip_runtime.h>

// LightGCN: N=U+I nodes, D=64 features, E edges (symmetrized to 2E directed).
// Strategy: build CSR per call (deg -> scan -> fill), then 3 atomic-free SpMM
// layers: one wave per output row, lane = feature dim. Norm weights computed
// on the fly from dis[] (cache-resident). acc fused into SpMM epilogue.

static constexpr int D = 64;
#define SCAN_T 256
#define SCAN_E 8
#define SCAN_CHUNK (SCAN_T * SCAN_E) // 2048

__global__ void degree_kernel(const int* __restrict__ eu, const int* __restrict__ ei,
                              int* __restrict__ deg, int E, int U) {
    int t = blockIdx.x * blockDim.x + threadIdx.x;
    if (t >= E) return;
    atomicAdd(&deg[eu[t]], 1);
    atomicAdd(&deg[U + ei[t]], 1);
}

__global__ void dis_kernel(const int* __restrict__ deg, float* __restrict__ dis, int N) {
    int t = blockIdx.x * blockDim.x + threadIdx.x;
    if (t >= N) return;
    dis[t] = 1.0f / sqrtf((float)deg[t] + 1e-7f);
}

__device__ __forceinline__ int block_incl_scan(int v) {
    __shared__ int lds[SCAN_T];
    int t = threadIdx.x;
    lds[t] = v;
    __syncthreads();
    for (int off = 1; off < SCAN_T; off <<= 1) {
        int add = (t >= off) ? lds[t - off] : 0;
        __syncthreads();
        lds[t] += add;
        __syncthreads();
    }
    return lds[t];
}

__global__ void scan_pass1(const int* __restrict__ deg, int* __restrict__ bsum, int N) {
    int base = blockIdx.x * SCAN_CHUNK + threadIdx.x * SCAN_E;
    int local = 0;
#pragma unroll
    for (int j = 0; j < SCAN_E; ++j) {
        int i = base + j;
        if (i < N) local += deg[i];
    }
    int incl = block_incl_scan(local);
    if (threadIdx.x == SCAN_T - 1) bsum[blockIdx.x] = incl;
}

__global__ void scan_pass2(int* __restrict__ bsum, int NB) {
    __shared__ int lds[128];
    int t = threadIdx.x;
    int v = (t < NB) ? bsum[t] : 0;
    lds[t] = v;
    __syncthreads();
    for (int off = 1; off < 128; off <<= 1) {
        int add = (t >= off) ? lds[t - off] : 0;
        __syncthreads();
        lds[t] += add;
        __syncthreads();
    }
    if (t < NB) bsum[t] = lds[t] - v; // exclusive
}

__global__ void scan_pass3(const int* __restrict__ deg, const int* __restrict__ bsum,
                           int* __restrict__ row_ptr, int* __restrict__ cursor, int N) {
    int base = blockIdx.x * SCAN_CHUNK + threadIdx.x * SCAN_E;
    int local = 0;
#pragma unroll
    for (int j = 0; j < SCAN_E; ++j) {
        int i = base + j;
        if (i < N) local += deg[i];
    }
    int incl = block_incl_scan(local);
    int run = bsum[blockIdx.x] + incl - local; // exclusive prefix for this thread
#pragma unroll
    for (int j = 0; j < SCAN_E; ++j) {
        int i = base + j;
        if (i < N) {
            row_ptr[i] = run;
            cursor[i] = run;
            run += deg[i];
        }
    }
}

__global__ void fill_kernel(const int* __restrict__ eu, const int* __restrict__ ei,
                            int* __restrict__ cursor, int* __restrict__ cols, int E, int U) {
    int t = blockIdx.x * blockDim.x + threadIdx.x;
    if (t >= E) return;
    int u = eu[t];
    int c = U + ei[t];
    int p0 = atomicAdd(&cursor[u], 1);
    cols[p0] = c;
    int p1 = atomicAdd(&cursor[c], 1);
    cols[p1] = u;
}

__global__ void init_kernel(const float* __restrict__ ue, const float* __restrict__ ie,
                            float* __restrict__ x, float* __restrict__ acc, int UD, int ND) {
    int t = blockIdx.x * blockDim.x + threadIdx.x;
    if (t >= ND) return;
    float v = (t < UD) ? ue[t] : ie[t - UD];
    x[t] = v;
    acc[t] = v;
}

// One wave per row. Lane = feature dim. Column indices loaded cooperatively
// (64/chunk) then broadcast via shfl -> inner gather loads are independent.
__global__ __launch_bounds__(256) void spmm_kernel(
        const int* __restrict__ row_ptr, const int* __restrict__ deg,
        const int* __restrict__ cols, const float* __restrict__ dis,
        const float* __restrict__ x, float* __restrict__ x_next,
        float* __restrict__ acc, int N) {
    int wid = blockIdx.x * (blockDim.x >> 6) + (threadIdx.x >> 6);
    int lane = threadIdx.x & 63;
    if (wid >= N) return;
    int start = row_ptr[wid];
    int cnt = deg[wid];
    float dr = dis[wid];
    float s = 0.0f;
    for (int chunk = 0; chunk < cnt; chunk += 64) {
        int idx = chunk + lane;
        int c = 0;
        float dv = 0.0f;
        if (idx < cnt) {
            c = cols[start + idx];
            dv = dis[c];
        }
        int jmax = min(64, cnt - chunk);
        for (int j = 0; j < jmax; ++j) {
            int cj = __shfl(c, j);
            float wj = __shfl(dv, j);
            s += (dr * wj) * x[cj * D + lane];
        }
    }
    int o = wid * D + lane;
    x_next[o] = s;
    acc[o] += s;
}

__global__ void scale_kernel(float* __restrict__ out, int ND) {
    int t = blockIdx.x * blockDim.x + threadIdx.x;
    if (t < ND) out[t] *= 0.25f;
}

extern "C" void kernel_launch(void* const* d_in, const int* in_sizes, int n_in,
                              void* d_out, int out_size, void* d_ws, size_t ws_size,
                              hipStream_t stream) {
    const float* ue = (const float*)d_in[0];
    const float* ie = (const float*)d_in[1];
    const int* eu = (const int*)d_in[2];
    const int* ei = (const int*)d_in[3];
    const int U = in_sizes[0] / D; // 100001
    const int I = in_sizes[1] / D; // 50001
    const int N = U + I;           // 150002
    const int E = in_sizes[2];     // 4,000,000
    float* out = (float*)d_out;

    char* ws = (char*)d_ws;
    auto alloc = [&](size_t bytes) {
        char* p = ws;
        ws += (bytes + 255) & ~(size_t)255;
        return p;
    };
    int* deg = (int*)alloc((size_t)N * 4);
    int* row_ptr = (int*)alloc((size_t)N * 4);
    int* cursor = (int*)alloc((size_t)N * 4);
    float* dis = (float*)alloc((size_t)N * 4);
    int* bsum = (int*)alloc(512);
    int* cols = (int*)alloc((size_t)2 * E * 4);
    float* xA = (float*)alloc((size_t)N * D * 4);
    float* xB = (float*)alloc((size_t)N * D * 4);

    hipMemsetAsync(deg, 0, (size_t)N * 4, stream);
    degree_kernel<<<(E + 255) / 256, 256, 0, stream>>>(eu, ei, deg, E, U);
    dis_kernel<<<(N + 255) / 256, 256, 0, stream>>>(deg, dis, N);

    int NB = (N + SCAN_CHUNK - 1) / SCAN_CHUNK; // 74 <= 128
    scan_pass1<<<NB, SCAN_T, 0, stream>>>(deg, bsum, N);
    scan_pass2<<<1, 128, 0, stream>>>(bsum, NB);
    scan_pass3<<<NB, SCAN_T, 0, stream>>>(deg, bsum, row_ptr, cursor, N);
    fill_kernel<<<(E + 255) / 256, 256, 0, stream>>>(eu, ei, cursor, cols, E, U);

    int ND = N * D, UD = U * D;
    init_kernel<<<(ND + 255) / 256, 256, 0, stream>>>(ue, ie, xA, out, UD, ND);

    float* x = xA;
    float* xn = xB;
    for (int l = 0; l < 3; ++l) {
        spmm_kernel<<<(N + 3) / 4, 256, 0, stream>>>(row_ptr, deg, cols, dis, x, xn, out, N);
        float* tmp = x; x = xn; xn = tmp;
    }
    scale_kernel<<<(ND + 255) / 256, 256, 0, stream>>>(out, ND);
}

// Round 2
// 1666.231 us; speedup vs baseline: 1.5007x; 1.5007x over previous
//
#include <hip/hip_runtime.h>

// LightGCN: N=U+I nodes, D=64 features, E edges (symmetrized to 2E directed).
// CSR built per call via two-level bucket sort (no 8M scattered global atomics,
// no 64B-line write amplification), then 3 atomic-free SpMM layers:
// one wave per row, lane = feature dim, norm weights on the fly from dis[].

static constexpr int D = 64;
#define BSHIFT 9
#define BROWS 512               // rows per bucket
#define KP 512                  // padded bucket count for scans
#define TILE 2048               // entries per bucket_scatter block (256 thr x 8)

// ---- Pass 0: per-bucket histogram (LDS-aggregated) ----
__global__ __launch_bounds__(256) void bucket_count(
        const int* __restrict__ eu, const int* __restrict__ ei,
        int* __restrict__ bcnt, int E, int U, int twoE) {
    __shared__ int h[KP];
    int tid = threadIdx.x;
    h[tid] = 0; h[tid + 256] = 0;
    __syncthreads();
    for (int e = blockIdx.x * blockDim.x + tid; e < twoE; e += gridDim.x * blockDim.x) {
        int r = (e < E) ? eu[e] : U + ei[e - E];
        atomicAdd(&h[r >> BSHIFT], 1);
    }
    __syncthreads();
    if (h[tid]) atomicAdd(&bcnt[tid], h[tid]);
    if (h[tid + 256]) atomicAdd(&bcnt[tid + 256], h[tid + 256]);
}

// ---- Pass 1: scan bucket counts -> bucket bases + global cursors ----
__global__ void bscan(const int* __restrict__ bcnt, int* __restrict__ bbase,
                      int* __restrict__ bcursor, int KB, int twoE) {
    __shared__ int s[KP];
    int tid = threadIdx.x; // 512 threads, 1 block
    int v = (tid < KB) ? bcnt[tid] : 0;
    s[tid] = v;
    __syncthreads();
    for (int off = 1; off < KP; off <<= 1) {
        int a = (tid >= off) ? s[tid - off] : 0;
        __syncthreads();
        s[tid] += a;
        __syncthreads();
    }
    int ex = s[tid] - v; // exclusive
    if (tid < KB) { bbase[tid] = ex; bcursor[tid] = ex; }
    if (tid == KB) bbase[tid] = twoE;
    if (tid >= KB) bcursor[tid] = 0;
}

// ---- Pass 2: scatter entries into bucket-grouped pairs buffer ----
// packed entry: (row & 511) << 18 | col   (col < 2^18)
__global__ __launch_bounds__(256) void bucket_scatter(
        const int* __restrict__ eu, const int* __restrict__ ei,
        int* __restrict__ bcursor, unsigned* __restrict__ pairs,
        int E, int U, int twoE) {
    __shared__ int hist[KP];           // counts -> local running cursor
    __shared__ int sbase[KP];          // tile-local exclusive base
    __shared__ int gbase[KP];          // reserved global base
    __shared__ unsigned staging[TILE];
    __shared__ unsigned short sb[TILE];
    int tid = threadIdx.x;
    hist[tid] = 0; hist[tid + 256] = 0;
    __syncthreads();
    int base_e = blockIdx.x * TILE;
    int bk[8]; unsigned pk[8];
#pragma unroll
    for (int k = 0; k < 8; ++k) {
        int e = base_e + k * 256 + tid;
        bk[k] = -1;
        if (e < twoE) {
            int r, c;
            if (e < E) { r = eu[e]; c = U + ei[e]; }
            else       { c = eu[e - E]; r = U + ei[e - E]; }
            int b = r >> BSHIFT;
            bk[k] = b;
            pk[k] = ((unsigned)(r & (BROWS - 1)) << 18) | (unsigned)c;
            atomicAdd(&hist[b], 1);
        }
    }
    __syncthreads();
    int c0 = hist[tid], c1 = hist[tid + 256];
    // inclusive Hillis-Steele scan over KP=512 (2 slots per thread)
    for (int off = 1; off < KP; off <<= 1) {
        int v0 = (tid >= off) ? hist[tid - off] : 0;
        int v1 = hist[tid + 256 - off];
        __syncthreads();
        hist[tid] += v0; hist[tid + 256] += v1;
        __syncthreads();
    }
    int e0 = hist[tid] - c0, e1 = hist[tid + 256] - c1;
    sbase[tid] = e0; sbase[tid + 256] = e1;
    if (c0 > 0) gbase[tid] = atomicAdd(&bcursor[tid], c0);
    if (c1 > 0) gbase[tid + 256] = atomicAdd(&bcursor[tid + 256], c1);
    hist[tid] = e0; hist[tid + 256] = e1;   // own-slot overwrite, no cross reads
    __syncthreads();
#pragma unroll
    for (int k = 0; k < 8; ++k) {
        if (bk[k] >= 0) {
            int pos = atomicAdd(&hist[bk[k]], 1);
            staging[pos] = pk[k];
            sb[pos] = (unsigned short)bk[k];
        }
    }
    __syncthreads();
    int tile_n = min(TILE, twoE - base_e);
#pragma unroll
    for (int k = 0; k < 8; ++k) {
        int j = k * 256 + tid;
        if (j < tile_n) {
            int b = sb[j];
            pairs[gbase[b] + (j - sbase[b])] = staging[j];
        }
    }
}

// ---- Pass 3: per-bucket counting sort -> deg/row_ptr/dis/cols ----
__global__ __launch_bounds__(256) void bucket_to_csr(
        const unsigned* __restrict__ pairs, const int* __restrict__ bbase,
        int* __restrict__ deg, int* __restrict__ row_ptr, float* __restrict__ dis,
        int* __restrict__ cols, int N) {
    __shared__ int cnt[BROWS];
    int tid = threadIdx.x;
    int b = blockIdx.x;
    int lo = bbase[b], hi = bbase[b + 1];
    cnt[tid] = 0; cnt[tid + 256] = 0;
    __syncthreads();
    for (int i = lo + tid; i < hi; i += 256) atomicAdd(&cnt[pairs[i] >> 18], 1);
    __syncthreads();
    int c0 = cnt[tid], c1 = cnt[tid + 256];
    for (int off = 1; off < BROWS; off <<= 1) {
        int v0 = (tid >= off) ? cnt[tid - off] : 0;
        int v1 = cnt[tid + 256 - off];
        __syncthreads();
        cnt[tid] += v0; cnt[tid + 256] += v1;
        __syncthreads();
    }
    int e0 = cnt[tid] - c0, e1 = cnt[tid + 256] - c1;
    int r0 = b << BSHIFT;
    if (r0 + tid < N) {
        deg[r0 + tid] = c0;
        row_ptr[r0 + tid] = lo + e0;
        dis[r0 + tid] = rsqrtf((float)c0 + 1e-7f);
    }
    if (r0 + 256 + tid < N) {
        deg[r0 + 256 + tid] = c1;
        row_ptr[r0 + 256 + tid] = lo + e1;
        dis[r0 + 256 + tid] = rsqrtf((float)c1 + 1e-7f);
    }
    cnt[tid] = e0; cnt[tid + 256] = e1;     // reuse as running cursors
    __syncthreads();
    for (int i = lo + tid; i < hi; i += 256) {
        unsigned p = pairs[i];
        int pos = atomicAdd(&cnt[p >> 18], 1);
        cols[lo + pos] = (int)(p & 0x3FFFFu);
    }
}

__global__ void init_kernel(const float* __restrict__ ue, const float* __restrict__ ie,
                            float* __restrict__ x, float* __restrict__ acc, int UD, int ND) {
    int t = blockIdx.x * blockDim.x + threadIdx.x;
    if (t >= ND) return;
    float v = (t < UD) ? ue[t] : ie[t - UD];
    x[t] = v;
    acc[t] = v;
}

// One wave per row. Lane = feature dim. Column indices loaded cooperatively
// (64/chunk) then broadcast via shfl -> inner gather loads are independent.
__global__ __launch_bounds__(256) void spmm_kernel(
        const int* __restrict__ row_ptr, const int* __restrict__ deg,
        const int* __restrict__ cols, const float* __restrict__ dis,
        const float* __restrict__ x, float* __restrict__ x_next,
        float* __restrict__ acc, int N) {
    int wid = blockIdx.x * (blockDim.x >> 6) + (threadIdx.x >> 6);
    int lane = threadIdx.x & 63;
    if (wid >= N) return;
    int start = row_ptr[wid];
    int cnt = deg[wid];
    float dr = dis[wid];
    float s = 0.0f;
    for (int chunk = 0; chunk < cnt; chunk += 64) {
        int idx = chunk + lane;
        int c = 0;
        float dv = 0.0f;
        if (idx < cnt) {
            c = cols[start + idx];
            dv = dis[c];
        }
        int jmax = min(64, cnt - chunk);
        for (int j = 0; j < jmax; ++j) {
            int cj = __shfl(c, j);
            float wj = __shfl(dv, j);
            s += (dr * wj) * x[cj * D + lane];
        }
    }
    int o = wid * D + lane;
    x_next[o] = s;
    acc[o] += s;
}

__global__ void scale_kernel(float* __restrict__ out, int ND) {
    int t = blockIdx.x * blockDim.x + threadIdx.x;
    if (t < ND) out[t] *= 0.25f;
}

extern "C" void kernel_launch(void* const* d_in, const int* in_sizes, int n_in,
                              void* d_out, int out_size, void* d_ws, size_t ws_size,
                              hipStream_t stream) {
    const float* ue = (const float*)d_in[0];
    const float* ie = (const float*)d_in[1];
    const int* eu = (const int*)d_in[2];
    const int* ei = (const int*)d_in[3];
    const int U = in_sizes[0] / D; // 100001
    const int I = in_sizes[1] / D; // 50001
    const int N = U + I;           // 150002
    const int E = in_sizes[2];     // 4,000,000
    const int twoE = 2 * E;
    const int KB = (N + BROWS - 1) / BROWS; // 293
    float* out = (float*)d_out;

    char* ws = (char*)d_ws;
    auto alloc = [&](size_t bytes) {
        char* p = ws;
        ws += (bytes + 255) & ~(size_t)255;
        return p;
    };
    int* deg = (int*)alloc((size_t)N * 4);
    int* row_ptr = (int*)alloc((size_t)N * 4);
    float* dis = (float*)alloc((size_t)N * 4);
    int* bcnt = (int*)alloc(KP * 4);
    int* bbase = (int*)alloc((KP + 1) * 4);
    int* bcursor = (int*)alloc(KP * 4);
    int* cols = (int*)alloc((size_t)twoE * 4);
    float* xA = (float*)alloc((size_t)N * D * 4);
    float* xB = (float*)alloc((size_t)N * D * 4);
    unsigned* pairs = (unsigned*)xB; // pairs (32MB) dead before xB first written

    hipMemsetAsync(bcnt, 0, KP * 4, stream);
    bucket_count<<<1024, 256, 0, stream>>>(eu, ei, bcnt, E, U, twoE);
    bscan<<<1, KP, 0, stream>>>(bcnt, bbase, bcursor, KB, twoE);
    bucket_scatter<<<(twoE + TILE - 1) / TILE, 256, 0, stream>>>(
        eu, ei, bcursor, pairs, E, U, twoE);
    bucket_to_csr<<<KB, 256, 0, stream>>>(pairs, bbase, deg, row_ptr, dis, cols, N);

    int ND = N * D, UD = U * D;
    init_kernel<<<(ND + 255) / 256, 256, 0, stream>>>(ue, ie, xA, out, UD, ND);

    float* x = xA;
    float* xn = xB;
    for (int l = 0; l < 3; ++l) {
        spmm_kernel<<<(N + 3) / 4, 256, 0, stream>>>(row_ptr, deg, cols, dis, x, xn, out, N);
        float* tmp = x; x = xn; xn = tmp;
    }
    scale_kernel<<<(ND + 255) / 256, 256, 0, stream>>>(out, ND);
}

// Round 3
// 1098.401 us; speedup vs baseline: 2.2766x; 1.5170x over previous
//
#include <hip/hip_runtime.h>

// LightGCN: N=U+I nodes, D=64 features, E edges (symmetrized to 2E directed).
// CSR built per call via two-level bucket sort, then 3 atomic-free SpMM layers.
// x stored as packed bf16x2 (row = 128B) -> halves random-gather bytes; acc fp32.
// SpMM: one wave per row; half-waves gather 2 neighbors/iter (128B contiguous each).

static constexpr int D = 64;
#define BSHIFT 9
#define BROWS 512               // rows per bucket
#define KP 512                  // padded bucket count for scans
#define TILE 2048               // entries per bucket_scatter block (256 thr x 8)

__device__ __forceinline__ float bflo(unsigned v) {
    unsigned u = v << 16;
    return __builtin_bit_cast(float, u);
}
__device__ __forceinline__ float bfhi(unsigned v) {
    unsigned u = v & 0xFFFF0000u;
    return __builtin_bit_cast(float, u);
}
__device__ __forceinline__ unsigned pack_bf16x2(float a, float b) {
    unsigned ua = __builtin_bit_cast(unsigned, a);
    unsigned ub = __builtin_bit_cast(unsigned, b);
    ua += 0x7FFFu + ((ua >> 16) & 1u);   // RNE
    ub += 0x7FFFu + ((ub >> 16) & 1u);
    return (ua >> 16) | (ub & 0xFFFF0000u);
}

// ---- Pass 0: per-bucket histogram (LDS-aggregated) ----
__global__ __launch_bounds__(256) void bucket_count(
        const int* __restrict__ eu, const int* __restrict__ ei,
        int* __restrict__ bcnt, int E, int U, int twoE) {
    __shared__ int h[KP];
    int tid = threadIdx.x;
    h[tid] = 0; h[tid + 256] = 0;
    __syncthreads();
    for (int e = blockIdx.x * blockDim.x + tid; e < twoE; e += gridDim.x * blockDim.x) {
        int r = (e < E) ? eu[e] : U + ei[e - E];
        atomicAdd(&h[r >> BSHIFT], 1);
    }
    __syncthreads();
    if (h[tid]) atomicAdd(&bcnt[tid], h[tid]);
    if (h[tid + 256]) atomicAdd(&bcnt[tid + 256], h[tid + 256]);
}

// ---- Pass 1: scan bucket counts -> bucket bases + global cursors ----
__global__ void bscan(const int* __restrict__ bcnt, int* __restrict__ bbase,
                      int* __restrict__ bcursor, int KB, int twoE) {
    __shared__ int s[KP];
    int tid = threadIdx.x; // 512 threads, 1 block
    int v = (tid < KB) ? bcnt[tid] : 0;
    s[tid] = v;
    __syncthreads();
    for (int off = 1; off < KP; off <<= 1) {
        int a = (tid >= off) ? s[tid - off] : 0;
        __syncthreads();
        s[tid] += a;
        __syncthreads();
    }
    int ex = s[tid] - v; // exclusive
    if (tid < KB) { bbase[tid] = ex; bcursor[tid] = ex; }
    if (tid == KB) bbase[tid] = twoE;
    if (tid >= KB) bcursor[tid] = 0;
}

// ---- Pass 2: scatter entries into bucket-grouped pairs buffer ----
// packed entry: (row & 511) << 18 | col   (col < 2^18)
__global__ __launch_bounds__(256) void bucket_scatter(
        const int* __restrict__ eu, const int* __restrict__ ei,
        int* __restrict__ bcursor, unsigned* __restrict__ pairs,
        int E, int U, int twoE) {
    __shared__ int hist[KP];           // counts -> local running cursor
    __shared__ int sbase[KP];          // tile-local exclusive base
    __shared__ int gbase[KP];          // reserved global base
    __shared__ unsigned staging[TILE];
    __shared__ unsigned short sb[TILE];
    int tid = threadIdx.x;
    hist[tid] = 0; hist[tid + 256] = 0;
    __syncthreads();
    int base_e = blockIdx.x * TILE;
    int bk[8]; unsigned pk[8];
#pragma unroll
    for (int k = 0; k < 8; ++k) {
        int e = base_e + k * 256 + tid;
        bk[k] = -1;
        if (e < twoE) {
            int r, c;
            if (e < E) { r = eu[e]; c = U + ei[e]; }
            else       { c = eu[e - E]; r = U + ei[e - E]; }
            int b = r >> BSHIFT;
            bk[k] = b;
            pk[k] = ((unsigned)(r & (BROWS - 1)) << 18) | (unsigned)c;
            atomicAdd(&hist[b], 1);
        }
    }
    __syncthreads();
    int c0 = hist[tid], c1 = hist[tid + 256];
    for (int off = 1; off < KP; off <<= 1) {
        int v0 = (tid >= off) ? hist[tid - off] : 0;
        int v1 = hist[tid + 256 - off];
        __syncthreads();
        hist[tid] += v0; hist[tid + 256] += v1;
        __syncthreads();
    }
    int e0 = hist[tid] - c0, e1 = hist[tid + 256] - c1;
    sbase[tid] = e0; sbase[tid + 256] = e1;
    if (c0 > 0) gbase[tid] = atomicAdd(&bcursor[tid], c0);
    if (c1 > 0) gbase[tid + 256] = atomicAdd(&bcursor[tid + 256], c1);
    hist[tid] = e0; hist[tid + 256] = e1;   // own-slot overwrite, no cross reads
    __syncthreads();
#pragma unroll
    for (int k = 0; k < 8; ++k) {
        if (bk[k] >= 0) {
            int pos = atomicAdd(&hist[bk[k]], 1);
            staging[pos] = pk[k];
            sb[pos] = (unsigned short)bk[k];
        }
    }
    __syncthreads();
    int tile_n = min(TILE, twoE - base_e);
#pragma unroll
    for (int k = 0; k < 8; ++k) {
        int j = k * 256 + tid;
        if (j < tile_n) {
            int b = sb[j];
            pairs[gbase[b] + (j - sbase[b])] = staging[j];
        }
    }
}

// ---- Pass 3: per-bucket counting sort -> deg/row_ptr/dis/cols ----
__global__ __launch_bounds__(256) void bucket_to_csr(
        const unsigned* __restrict__ pairs, const int* __restrict__ bbase,
        int* __restrict__ deg, int* __restrict__ row_ptr, float* __restrict__ dis,
        int* __restrict__ cols, int N) {
    __shared__ int cnt[BROWS];
    int tid = threadIdx.x;
    int b = blockIdx.x;
    int lo = bbase[b], hi = bbase[b + 1];
    cnt[tid] = 0; cnt[tid + 256] = 0;
    __syncthreads();
    for (int i = lo + tid; i < hi; i += 256) atomicAdd(&cnt[pairs[i] >> 18], 1);
    __syncthreads();
    int c0 = cnt[tid], c1 = cnt[tid + 256];
    for (int off = 1; off < BROWS; off <<= 1) {
        int v0 = (tid >= off) ? cnt[tid - off] : 0;
        int v1 = cnt[tid + 256 - off];
        __syncthreads();
        cnt[tid] += v0; cnt[tid + 256] += v1;
        __syncthreads();
    }
    int e0 = cnt[tid] - c0, e1 = cnt[tid + 256] - c1;
    int r0 = b << BSHIFT;
    if (r0 + tid < N) {
        deg[r0 + tid] = c0;
        row_ptr[r0 + tid] = lo + e0;
        dis[r0 + tid] = rsqrtf((float)c0 + 1e-7f);
    }
    if (r0 + 256 + tid < N) {
        deg[r0 + 256 + tid] = c1;
        row_ptr[r0 + 256 + tid] = lo + e1;
        dis[r0 + 256 + tid] = rsqrtf((float)c1 + 1e-7f);
    }
    cnt[tid] = e0; cnt[tid + 256] = e1;     // reuse as running cursors
    __syncthreads();
    for (int i = lo + tid; i < hi; i += 256) {
        unsigned p = pairs[i];
        int pos = atomicAdd(&cnt[p >> 18], 1);
        cols[lo + pos] = (int)(p & 0x3FFFFu);
    }
}

// t handles feature pair (2t, 2t+1): acc fp32 (float2) + x bf16x2.
__global__ void init_kernel(const float* __restrict__ ue, const float* __restrict__ ie,
                            unsigned* __restrict__ x2, float2* __restrict__ acc2,
                            int UD2, int ND2) {
    int t = blockIdx.x * blockDim.x + threadIdx.x;
    if (t >= ND2) return;
    const float* src = (t < UD2) ? ue : ie;
    int tt = (t < UD2) ? t : t - UD2;
    float v0 = src[2 * tt];
    float v1 = src[2 * tt + 1];
    acc2[t] = make_float2(v0, v1);
    x2[t] = pack_bf16x2(v0, v1);
}

// One wave per row. lane = (neighbor-half, dim-pair). Half-waves 0/1 gather
// two different neighbors per iteration, each 128B contiguous (bf16x2 row).
// Cross-half shfl_xor(32) reduce at the end; acc (fp32) fused, final scale fused.
__global__ __launch_bounds__(256) void spmm_kernel(
        const int* __restrict__ row_ptr, const int* __restrict__ deg,
        const int* __restrict__ cols, const float* __restrict__ dis,
        const unsigned* __restrict__ x2, unsigned* __restrict__ x_next2,
        float2* __restrict__ acc2, int N, float final_scale) {
    int wid = blockIdx.x * (blockDim.x >> 6) + (threadIdx.x >> 6);
    int lane = threadIdx.x & 63;
    if (wid >= N) return;
    int half = lane >> 5;      // which neighbor of the pair
    int dp = lane & 31;        // dim-pair index
    int start = row_ptr[wid];
    int cnt = deg[wid];
    float dr = dis[wid];
    float sx = 0.0f, sy = 0.0f;
    for (int chunk = 0; chunk < cnt; chunk += 64) {
        int idx = chunk + lane;
        int c = 0;
        float dv = 0.0f;
        if (idx < cnt) {
            c = cols[start + idx];
            dv = dis[c];
        }
        int jmax = min(64, cnt - chunk);
        int jmax2 = jmax & ~1;
        for (int j = 0; j < jmax2; j += 2) {
            int src = j + half;
            int cj = __shfl(c, src);
            float wj = __shfl(dv, src);
            unsigned v = x2[cj * 32 + dp];
            sx += wj * bflo(v);
            sy += wj * bfhi(v);
        }
        if (jmax & 1) {
            int src = jmax - 1;
            int cj = __shfl(c, src);
            float wj = __shfl(dv, src);
            if (half == 0) {
                unsigned v = x2[cj * 32 + dp];
                sx += wj * bflo(v);
                sy += wj * bfhi(v);
            }
        }
    }
    sx = dr * (sx + __shfl_xor(sx, 32));
    sy = dr * (sy + __shfl_xor(sy, 32));
    if (half == 0) {
        int o = wid * 32 + dp;
        x_next2[o] = pack_bf16x2(sx, sy);
        float2 a = acc2[o];
        a.x = (a.x + sx) * final_scale;
        a.y = (a.y + sy) * final_scale;
        acc2[o] = a;
    }
}

extern "C" void kernel_launch(void* const* d_in, const int* in_sizes, int n_in,
                              void* d_out, int out_size, void* d_ws, size_t ws_size,
                              hipStream_t stream) {
    const float* ue = (const float*)d_in[0];
    const float* ie = (const float*)d_in[1];
    const int* eu = (const int*)d_in[2];
    const int* ei = (const int*)d_in[3];
    const int U = in_sizes[0] / D; // 100001
    const int I = in_sizes[1] / D; // 50001
    const int N = U + I;           // 150002
    const int E = in_sizes[2];     // 4,000,000
    const int twoE = 2 * E;
    const int KB = (N + BROWS - 1) / BROWS; // 293
    float* out = (float*)d_out;

    char* ws = (char*)d_ws;
    auto alloc = [&](size_t bytes) {
        char* p = ws;
        ws += (bytes + 255) & ~(size_t)255;
        return p;
    };
    int* deg = (int*)alloc((size_t)N * 4);
    int* row_ptr = (int*)alloc((size_t)N * 4);
    float* dis = (float*)alloc((size_t)N * 4);
    int* bcnt = (int*)alloc(KP * 4);
    int* bbase = (int*)alloc((KP + 1) * 4);
    int* bcursor = (int*)alloc(KP * 4);
    int* cols = (int*)alloc((size_t)twoE * 4);
    unsigned* pairs = (unsigned*)alloc((size_t)twoE * 4);
    unsigned* xA = (unsigned*)alloc((size_t)N * 32 * 4); // bf16x2 packed
    unsigned* xB = (unsigned*)alloc((size_t)N * 32 * 4);

    hipMemsetAsync(bcnt, 0, KP * 4, stream);
    bucket_count<<<1024, 256, 0, stream>>>(eu, ei, bcnt, E, U, twoE);
    bscan<<<1, KP, 0, stream>>>(bcnt, bbase, bcursor, KB, twoE);
    bucket_scatter<<<(twoE + TILE - 1) / TILE, 256, 0, stream>>>(
        eu, ei, bcursor, pairs, E, U, twoE);
    bucket_to_csr<<<KB, 256, 0, stream>>>(pairs, bbase, deg, row_ptr, dis, cols, N);

    int ND2 = N * 32, UD2 = U * 32;
    init_kernel<<<(ND2 + 255) / 256, 256, 0, stream>>>(ue, ie, xA, (float2*)out, UD2, ND2);

    unsigned* x = xA;
    unsigned* xn = xB;
    for (int l = 0; l < 3; ++l) {
        float fs = (l == 2) ? 0.25f : 1.0f;
        spmm_kernel<<<(N + 3) / 4, 256, 0, stream>>>(
            row_ptr, deg, cols, dis, x, xn, (float2*)out, N, fs);
        unsigned* tmp = x; x = xn; xn = tmp;
    }
}

// Round 4
// 811.457 us; speedup vs baseline: 3.0816x; 1.3536x over previous
//
#include <hip/hip_runtime.h>

// LightGCN: N=U+I nodes, D=64 features, E edges (symmetrized to 2E directed).
// CSR built per call via two-level bucket sort with rows PADDED to multiples of
// 4 using a sentinel zero-row (index N) -> branch-free SpMM inner loop.
// x stored pre-scaled: xs[c] = dis[c]*x[c] (bf16x2 packed, row = 128B) so the
// SpMM gather needs no per-edge weight: S = sum xs[c]; x_new = dr*S;
// xs_next = dr^2*S. One wave per row; lane=(n,dp): 4 neighbors per uint2 load.

static constexpr int D = 64;
#define BSHIFT 9
#define BROWS 512               // rows per bucket
#define KP 512                  // padded bucket count for scans
#define TILE 2048               // entries per bucket_scatter block (256 thr x 8)

__device__ __forceinline__ float bflo(unsigned v) {
    unsigned u = v << 16;
    return __builtin_bit_cast(float, u);
}
__device__ __forceinline__ float bfhi(unsigned v) {
    unsigned u = v & 0xFFFF0000u;
    return __builtin_bit_cast(float, u);
}
__device__ __forceinline__ unsigned pack_bf16x2(float a, float b) {
    unsigned ua = __builtin_bit_cast(unsigned, a);
    unsigned ub = __builtin_bit_cast(unsigned, b);
    ua += 0x7FFFu + ((ua >> 16) & 1u);   // RNE
    ub += 0x7FFFu + ((ub >> 16) & 1u);
    return (ua >> 16) | (ub & 0xFFFF0000u);
}

// ---- Pass 0: per-bucket histogram (LDS-aggregated) ----
__global__ __launch_bounds__(256) void bucket_count(
        const int* __restrict__ eu, const int* __restrict__ ei,
        int* __restrict__ bcnt, int E, int U, int twoE) {
    __shared__ int h[KP];
    int tid = threadIdx.x;
    h[tid] = 0; h[tid + 256] = 0;
    __syncthreads();
    for (int e = blockIdx.x * blockDim.x + tid; e < twoE; e += gridDim.x * blockDim.x) {
        int r = (e < E) ? eu[e] : U + ei[e - E];
        atomicAdd(&h[r >> BSHIFT], 1);
    }
    __syncthreads();
    if (h[tid]) atomicAdd(&bcnt[tid], h[tid]);
    if (h[tid + 256]) atomicAdd(&bcnt[tid + 256], h[tid + 256]);
}

// ---- Pass 1: scan bucket counts -> raw bucket bases + global cursors ----
__global__ void bscan(const int* __restrict__ bcnt, int* __restrict__ bbase,
                      int* __restrict__ bcursor, int KB, int twoE) {
    __shared__ int s[KP];
    int tid = threadIdx.x; // 512 threads, 1 block
    int v = (tid < KB) ? bcnt[tid] : 0;
    s[tid] = v;
    __syncthreads();
    for (int off = 1; off < KP; off <<= 1) {
        int a = (tid >= off) ? s[tid - off] : 0;
        __syncthreads();
        s[tid] += a;
        __syncthreads();
    }
    int ex = s[tid] - v; // exclusive
    if (tid < KB) { bbase[tid] = ex; bcursor[tid] = ex; }
    if (tid == KB) bbase[tid] = twoE;
    if (tid >= KB) bcursor[tid] = 0;
}

// ---- Pass 2: scatter entries into bucket-grouped pairs buffer ----
// packed entry: (row & 511) << 18 | col   (col < 2^18)
__global__ __launch_bounds__(256) void bucket_scatter(
        const int* __restrict__ eu, const int* __restrict__ ei,
        int* __restrict__ bcursor, unsigned* __restrict__ pairs,
        int E, int U, int twoE) {
    __shared__ int hist[KP];           // counts -> local running cursor
    __shared__ int sbase[KP];          // tile-local exclusive base
    __shared__ int gbase[KP];          // reserved global base
    __shared__ unsigned staging[TILE];
    __shared__ unsigned short sb[TILE];
    int tid = threadIdx.x;
    hist[tid] = 0; hist[tid + 256] = 0;
    __syncthreads();
    int base_e = blockIdx.x * TILE;
    int bk[8]; unsigned pk[8];
#pragma unroll
    for (int k = 0; k < 8; ++k) {
        int e = base_e + k * 256 + tid;
        bk[k] = -1;
        if (e < twoE) {
            int r, c;
            if (e < E) { r = eu[e]; c = U + ei[e]; }
            else       { c = eu[e - E]; r = U + ei[e - E]; }
            int b = r >> BSHIFT;
            bk[k] = b;
            pk[k] = ((unsigned)(r & (BROWS - 1)) << 18) | (unsigned)c;
            atomicAdd(&hist[b], 1);
        }
    }
    __syncthreads();
    int c0 = hist[tid], c1 = hist[tid + 256];
    for (int off = 1; off < KP; off <<= 1) {
        int v0 = (tid >= off) ? hist[tid - off] : 0;
        int v1 = hist[tid + 256 - off];
        __syncthreads();
        hist[tid] += v0; hist[tid + 256] += v1;
        __syncthreads();
    }
    int e0 = hist[tid] - c0, e1 = hist[tid + 256] - c1;
    sbase[tid] = e0; sbase[tid + 256] = e1;
    if (c0 > 0) gbase[tid] = atomicAdd(&bcursor[tid], c0);
    if (c1 > 0) gbase[tid + 256] = atomicAdd(&bcursor[tid + 256], c1);
    hist[tid] = e0; hist[tid + 256] = e1;   // own-slot overwrite, no cross reads
    __syncthreads();
#pragma unroll
    for (int k = 0; k < 8; ++k) {
        if (bk[k] >= 0) {
            int pos = atomicAdd(&hist[bk[k]], 1);
            staging[pos] = pk[k];
            sb[pos] = (unsigned short)bk[k];
        }
    }
    __syncthreads();
    int tile_n = min(TILE, twoE - base_e);
#pragma unroll
    for (int k = 0; k < 8; ++k) {
        int j = k * 256 + tid;
        if (j < tile_n) {
            int b = sb[j];
            pairs[gbase[b] + (j - sbase[b])] = staging[j];
        }
    }
}

// ---- Pass 3a: per-bucket row counts -> deg, dis, local PADDED offsets, pT[b] ----
__global__ __launch_bounds__(256) void csr_pass_a(
        const unsigned* __restrict__ pairs, const int* __restrict__ bbase,
        int* __restrict__ deg, int* __restrict__ lrow, float* __restrict__ dis,
        int* __restrict__ pT, int N) {
    __shared__ int cnt[BROWS];
    __shared__ int s[KP];
    int tid = threadIdx.x;
    int b = blockIdx.x;
    int lo = bbase[b], hi = bbase[b + 1];
    cnt[tid] = 0; cnt[tid + 256] = 0;
    __syncthreads();
    for (int i = lo + tid; i < hi; i += 256) atomicAdd(&cnt[pairs[i] >> 18], 1);
    __syncthreads();
    int c0 = cnt[tid], c1 = cnt[tid + 256];
    int p0 = (c0 + 3) & ~3, p1 = (c1 + 3) & ~3;
    s[tid] = p0; s[tid + 256] = p1;
    __syncthreads();
    for (int off = 1; off < KP; off <<= 1) {
        int v0 = (tid >= off) ? s[tid - off] : 0;
        int v1 = s[tid + 256 - off];
        __syncthreads();
        s[tid] += v0; s[tid + 256] += v1;
        __syncthreads();
    }
    int e0 = s[tid] - p0, e1 = s[tid + 256] - p1;
    int r0 = b << BSHIFT;
    if (r0 + tid < N) {
        deg[r0 + tid] = c0; lrow[r0 + tid] = e0;
        dis[r0 + tid] = rsqrtf((float)c0 + 1e-7f);
    }
    if (r0 + 256 + tid < N) {
        deg[r0 + 256 + tid] = c1; lrow[r0 + 256 + tid] = e1;
        dis[r0 + 256 + tid] = rsqrtf((float)c1 + 1e-7f);
    }
    if (tid == 0) pT[b] = s[KP - 1];
}

// ---- Pass 3b': exclusive scan of per-bucket padded totals ----
__global__ void pscan(const int* __restrict__ pT, int* __restrict__ pbase, int KB) {
    __shared__ int s[KP];
    int tid = threadIdx.x;
    int v = (tid < KB) ? pT[tid] : 0;
    s[tid] = v;
    __syncthreads();
    for (int off = 1; off < KP; off <<= 1) {
        int a = (tid >= off) ? s[tid - off] : 0;
        __syncthreads();
        s[tid] += a;
        __syncthreads();
    }
    if (tid < KB) pbase[tid] = s[tid] - v;
}

// ---- Pass 3c: scatter cols into padded CSR; fill pad slots with sentinel N ----
__global__ __launch_bounds__(256) void csr_pass_b(
        const unsigned* __restrict__ pairs, const int* __restrict__ bbase,
        const int* __restrict__ pbase, const int* __restrict__ deg,
        int* __restrict__ row_ptr, int* __restrict__ cols, int N) {
    __shared__ int cur[BROWS];
    __shared__ int fin[BROWS];
    int tid = threadIdx.x;
    int b = blockIdx.x;
    int lo = bbase[b], hi = bbase[b + 1];
    int pb = pbase[b];
    int r0 = b << BSHIFT;
    {
        int r = r0 + tid;
        int l = (r < N) ? row_ptr[r] : 0;
        int c = (r < N) ? deg[r] : 0;
        cur[tid] = l; fin[tid] = l + ((c + 3) & ~3);
        if (r < N) row_ptr[r] = pb + l;          // finalize global padded base
        r = r0 + 256 + tid;
        l = (r < N) ? row_ptr[r] : 0;
        c = (r < N) ? deg[r] : 0;
        cur[tid + 256] = l; fin[tid + 256] = l + ((c + 3) & ~3);
        if (r < N) row_ptr[r] = pb + l;
    }
    __syncthreads();
    for (int i = lo + tid; i < hi; i += 256) {
        unsigned p = pairs[i];
        int pos = atomicAdd(&cur[p >> 18], 1);
        cols[pb + pos] = (int)(p & 0x3FFFFu);
    }
    __syncthreads();
    for (int i = cur[tid]; i < fin[tid]; ++i) cols[pb + i] = N;          // sentinel
    for (int i = cur[tid + 256]; i < fin[tid + 256]; ++i) cols[pb + i] = N;
}

// t handles one bf16x2 dword (2 dims). xs = dis*emb pre-scaled; row N zeroed.
__global__ void init_kernel(const float* __restrict__ ue, const float* __restrict__ ie,
                            const float* __restrict__ dis, unsigned* __restrict__ xs,
                            float2* __restrict__ acc2, int UD2, int ND2) {
    int t = blockIdx.x * blockDim.x + threadIdx.x;
    if (t >= ND2 + 32) return;
    if (t >= ND2) { xs[t] = 0u; return; }    // sentinel zero-row N
    const float* src = (t < UD2) ? ue : ie;
    int tt = (t < UD2) ? t : t - UD2;
    float v0 = src[2 * tt];
    float v1 = src[2 * tt + 1];
    acc2[t] = make_float2(v0, v1);
    float dv = dis[t >> 5];
    xs[t] = pack_bf16x2(dv * v0, dv * v1);
}

// One wave per row. lane = (n = lane>>4 neighbor slot, dp = lane&15 uint2 idx).
// One uint2 load covers 4 neighbor rows per instruction; one ds_bpermute per
// quad broadcasts the 4 cols. Rows padded to x4 with sentinel -> no tail code.
__global__ __launch_bounds__(256) void spmm_kernel(
        const int* __restrict__ row_ptr, const int* __restrict__ deg,
        const float* __restrict__ dis, const int* __restrict__ cols,
        const unsigned* __restrict__ xs, unsigned* __restrict__ xs_next,
        float4* __restrict__ acc4, int N, float final_scale) {
    int wid = blockIdx.x * 4 + (threadIdx.x >> 6);
    if (wid >= N) return;
    int lane = threadIdx.x & 63;
    int n4 = lane >> 4;
    int dp = lane & 15;
    int start = row_ptr[wid];
    int cntp = (deg[wid] + 3) & ~3;
    float dr = dis[wid];
    const int* colp = cols + start;
    int vbase = n4 << 2;       // bpermute byte addr component
    int dpo = dp << 1;         // dword offset within row
    float s0 = 0.f, s1 = 0.f, s2 = 0.f, s3 = 0.f;
    for (int chunk = 0; chunk < cntp; chunk += 64) {
        int cv = colp[chunk + lane];           // over-read OK (slack at end)
        int nq = min(64, cntp - chunk) >> 2;
        for (int q = 0; q < nq; ++q) {
            int co = __builtin_amdgcn_ds_bpermute((q << 4) + vbase, cv);
            const uint2* p = (const uint2*)(xs + (((unsigned)co) << 5) + dpo);
            uint2 v = *p;
            s0 += bflo(v.x); s1 += bfhi(v.x);
            s2 += bflo(v.y); s3 += bfhi(v.y);
        }
    }
    s0 += __shfl_xor(s0, 16); s1 += __shfl_xor(s1, 16);
    s2 += __shfl_xor(s2, 16); s3 += __shfl_xor(s3, 16);
    s0 += __shfl_xor(s0, 32); s1 += __shfl_xor(s1, 32);
    s2 += __shfl_xor(s2, 32); s3 += __shfl_xor(s3, 32);
    if (n4 == 0) {
        float x0 = dr * s0, x1 = dr * s1, x2 = dr * s2, x3 = dr * s3;
        int o = (wid << 4) + dp;
        uint2 w;
        w.x = pack_bf16x2(dr * x0, dr * x1);   // xs_next = dr^2 * S
        w.y = pack_bf16x2(dr * x2, dr * x3);
        ((uint2*)xs_next)[o] = w;
        float4 a = acc4[o];
        a.x = (a.x + x0) * final_scale;
        a.y = (a.y + x1) * final_scale;
        a.z = (a.z + x2) * final_scale;
        a.w = (a.w + x3) * final_scale;
        acc4[o] = a;
    }
}

extern "C" void kernel_launch(void* const* d_in, const int* in_sizes, int n_in,
                              void* d_out, int out_size, void* d_ws, size_t ws_size,
                              hipStream_t stream) {
    const float* ue = (const float*)d_in[0];
    const float* ie = (const float*)d_in[1];
    const int* eu = (const int*)d_in[2];
    const int* ei = (const int*)d_in[3];
    const int U = in_sizes[0] / D; // 100001
    const int I = in_sizes[1] / D; // 50001
    const int N = U + I;           // 150002
    const int E = in_sizes[2];     // 4,000,000
    const int twoE = 2 * E;
    const int KB = (N + BROWS - 1) / BROWS; // 293
    float* out = (float*)d_out;

    char* ws = (char*)d_ws;
    auto alloc = [&](size_t bytes) {
        char* p = ws;
        ws += (bytes + 255) & ~(size_t)255;
        return p;
    };
    int* deg = (int*)alloc((size_t)N * 4);
    int* row_ptr = (int*)alloc((size_t)N * 4);
    float* dis = (float*)alloc((size_t)N * 4);
    int* bcnt = (int*)alloc(KP * 4);
    int* bbase = (int*)alloc((KP + 1) * 4);
    int* bcursor = (int*)alloc(KP * 4);
    int* pT = (int*)alloc(KP * 4);
    int* pbase = (int*)alloc(KP * 4);
    int* cols = (int*)alloc(((size_t)twoE + 3 * (size_t)N + 256) * 4); // padded + slack
    unsigned* pairs = (unsigned*)alloc((size_t)twoE * 4);
    unsigned* xsA = (unsigned*)alloc(((size_t)N + 1) * 32 * 4); // bf16x2, +sentinel row
    unsigned* xsB = (unsigned*)alloc(((size_t)N + 1) * 32 * 4);

    hipMemsetAsync(bcnt, 0, KP * 4, stream);
    bucket_count<<<1024, 256, 0, stream>>>(eu, ei, bcnt, E, U, twoE);
    bscan<<<1, KP, 0, stream>>>(bcnt, bbase, bcursor, KB, twoE);
    bucket_scatter<<<(twoE + TILE - 1) / TILE, 256, 0, stream>>>(
        eu, ei, bcursor, pairs, E, U, twoE);
    csr_pass_a<<<KB, 256, 0, stream>>>(pairs, bbase, deg, row_ptr, dis, pT, N);
    pscan<<<1, KP, 0, stream>>>(pT, pbase, KB);
    csr_pass_b<<<KB, 256, 0, stream>>>(pairs, bbase, pbase, deg, row_ptr, cols, N);

    int ND2 = N * 32, UD2 = U * 32;
    init_kernel<<<(ND2 + 32 + 255) / 256, 256, 0, stream>>>(
        ue, ie, dis, xsA, (float2*)out, UD2, ND2);

    unsigned* x = xsA;
    unsigned* xn = xsB;
    for (int l = 0; l < 3; ++l) {
        float fs = (l == 2) ? 0.25f : 1.0f;
        spmm_kernel<<<(N + 3) / 4, 256, 0, stream>>>(
            row_ptr, deg, dis, cols, x, xn, (float4*)out, N, fs);
        unsigned* tmp = x; x = xn; xn = tmp;
    }
}

// Round 5
// 683.518 us; speedup vs baseline: 3.6584x; 1.1872x over previous
//
#include <hip/hip_runtime.h>

// LightGCN: N=U+I nodes, D=64 features, E edges (symmetrized to 2E directed).
// CSR built per call via bucket sort with rows PADDED to multiples of 8 using a
// sentinel zero-row (index N) -> branch-free SpMM inner loop.
// x stored pre-scaled: xs[c] = dis[c]*x[c] (bf16x2 packed, row = 128B):
// S = sum xs[c]; x_new = dr*S; xs_next = dr^2*S.
// SpMM: one wave per row; lane=(n8,dp): 8 neighbors per uint4 (16B) load.
// Padded CSR bases are deterministic (bbase[b] + 3584*b) so the whole
// counting-sort stage is ONE kernel (no pscan / second scan pass).

static constexpr int D = 64;
#define BSHIFT 9
#define BROWS 512               // rows per bucket
#define KP 512                  // padded bucket count for scans
#define TILE 2048               // entries per bucket_scatter block (256 thr x 8)
#define PADSLACK (7 * BROWS)    // max pad growth per bucket (rows pad to x8)

__device__ __forceinline__ float bflo(unsigned v) {
    unsigned u = v << 16;
    return __builtin_bit_cast(float, u);
}
__device__ __forceinline__ float bfhi(unsigned v) {
    unsigned u = v & 0xFFFF0000u;
    return __builtin_bit_cast(float, u);
}
__device__ __forceinline__ unsigned pack_bf16x2(float a, float b) {
    unsigned ua = __builtin_bit_cast(unsigned, a);
    unsigned ub = __builtin_bit_cast(unsigned, b);
    ua += 0x7FFFu + ((ua >> 16) & 1u);   // RNE
    ub += 0x7FFFu + ((ub >> 16) & 1u);
    return (ua >> 16) | (ub & 0xFFFF0000u);
}

// ---- Pass 0: per-bucket histogram (LDS-aggregated) ----
__global__ __launch_bounds__(256) void bucket_count(
        const int* __restrict__ eu, const int* __restrict__ ei,
        int* __restrict__ bcnt, int E, int U, int twoE) {
    __shared__ int h[KP];
    int tid = threadIdx.x;
    h[tid] = 0; h[tid + 256] = 0;
    __syncthreads();
    for (int e = blockIdx.x * blockDim.x + tid; e < twoE; e += gridDim.x * blockDim.x) {
        int r = (e < E) ? eu[e] : U + ei[e - E];
        atomicAdd(&h[r >> BSHIFT], 1);
    }
    __syncthreads();
    if (h[tid]) atomicAdd(&bcnt[tid], h[tid]);
    if (h[tid + 256]) atomicAdd(&bcnt[tid + 256], h[tid + 256]);
}

// ---- Pass 1: scan bucket counts -> raw bucket bases + global cursors ----
__global__ void bscan(const int* __restrict__ bcnt, int* __restrict__ bbase,
                      int* __restrict__ bcursor, int KB, int twoE) {
    __shared__ int s[KP];
    int tid = threadIdx.x; // 512 threads, 1 block
    int v = (tid < KB) ? bcnt[tid] : 0;
    s[tid] = v;
    __syncthreads();
    for (int off = 1; off < KP; off <<= 1) {
        int a = (tid >= off) ? s[tid - off] : 0;
        __syncthreads();
        s[tid] += a;
        __syncthreads();
    }
    int ex = s[tid] - v; // exclusive
    if (tid < KB) { bbase[tid] = ex; bcursor[tid] = ex; }
    if (tid == KB) bbase[tid] = twoE;
    if (tid >= KB) bcursor[tid] = 0;
}

// ---- Pass 2: scatter entries into bucket-grouped pairs buffer ----
// packed entry: (row & 511) << 18 | col   (col < 2^18)
__global__ __launch_bounds__(256) void bucket_scatter(
        const int* __restrict__ eu, const int* __restrict__ ei,
        int* __restrict__ bcursor, unsigned* __restrict__ pairs,
        int E, int U, int twoE) {
    __shared__ int hist[KP];           // counts -> local running cursor
    __shared__ int sbase[KP];          // tile-local exclusive base
    __shared__ int gbase[KP];          // reserved global base
    __shared__ unsigned staging[TILE];
    __shared__ unsigned short sb[TILE];
    int tid = threadIdx.x;
    hist[tid] = 0; hist[tid + 256] = 0;
    __syncthreads();
    int base_e = blockIdx.x * TILE;
    int bk[8]; unsigned pk[8];
#pragma unroll
    for (int k = 0; k < 8; ++k) {
        int e = base_e + k * 256 + tid;
        bk[k] = -1;
        if (e < twoE) {
            int r, c;
            if (e < E) { r = eu[e]; c = U + ei[e]; }
            else       { c = eu[e - E]; r = U + ei[e - E]; }
            int b = r >> BSHIFT;
            bk[k] = b;
            pk[k] = ((unsigned)(r & (BROWS - 1)) << 18) | (unsigned)c;
            atomicAdd(&hist[b], 1);
        }
    }
    __syncthreads();
    int c0 = hist[tid], c1 = hist[tid + 256];
    for (int off = 1; off < KP; off <<= 1) {
        int v0 = (tid >= off) ? hist[tid - off] : 0;
        int v1 = hist[tid + 256 - off];
        __syncthreads();
        hist[tid] += v0; hist[tid + 256] += v1;
        __syncthreads();
    }
    int e0 = hist[tid] - c0, e1 = hist[tid + 256] - c1;
    sbase[tid] = e0; sbase[tid + 256] = e1;
    if (c0 > 0) gbase[tid] = atomicAdd(&bcursor[tid], c0);
    if (c1 > 0) gbase[tid + 256] = atomicAdd(&bcursor[tid + 256], c1);
    hist[tid] = e0; hist[tid + 256] = e1;   // own-slot overwrite, no cross reads
    __syncthreads();
#pragma unroll
    for (int k = 0; k < 8; ++k) {
        if (bk[k] >= 0) {
            int pos = atomicAdd(&hist[bk[k]], 1);
            staging[pos] = pk[k];
            sb[pos] = (unsigned short)bk[k];
        }
    }
    __syncthreads();
    int tile_n = min(TILE, twoE - base_e);
#pragma unroll
    for (int k = 0; k < 8; ++k) {
        int j = k * 256 + tid;
        if (j < tile_n) {
            int b = sb[j];
            pairs[gbase[b] + (j - sbase[b])] = staging[j];
        }
    }
}

// ---- Pass 3 (merged): per-bucket counting sort -> deg/row_ptr/dis/cols ----
// 512 threads, one thread per row in bucket. Padded base = bbase[b] + 3584*b.
__global__ __launch_bounds__(512) void csr_build(
        const unsigned* __restrict__ pairs, const int* __restrict__ bbase,
        int* __restrict__ deg, int* __restrict__ row_ptr, float* __restrict__ dis,
        int* __restrict__ cols, int N) {
    __shared__ int cnt[BROWS];
    __shared__ int cur[BROWS];
    __shared__ int fin[BROWS];
    int tid = threadIdx.x;
    int b = blockIdx.x;
    int lo = bbase[b], hi = bbase[b + 1];
    int cbase = lo + PADSLACK * b;
    cnt[tid] = 0;
    __syncthreads();
    for (int i = lo + tid; i < hi; i += 512) atomicAdd(&cnt[pairs[i] >> 18], 1);
    __syncthreads();
    int c = cnt[tid];
    int p = (c + 7) & ~7;
    cnt[tid] = p;
    __syncthreads();
    for (int off = 1; off < BROWS; off <<= 1) {
        int a = (tid >= off) ? cnt[tid - off] : 0;
        __syncthreads();
        cnt[tid] += a;
        __syncthreads();
    }
    int e = cnt[tid] - p; // exclusive padded offset within bucket
    int r = (b << BSHIFT) + tid;
    if (r < N) {
        deg[r] = c;
        row_ptr[r] = cbase + e;
        dis[r] = rsqrtf((float)c + 1e-7f);
    }
    cur[tid] = e;
    fin[tid] = e + p;
    __syncthreads();
    for (int i = lo + tid; i < hi; i += 512) {
        unsigned pe = pairs[i];
        int pos = atomicAdd(&cur[pe >> 18], 1);
        cols[cbase + pos] = (int)(pe & 0x3FFFFu);
    }
    __syncthreads();
    for (int i = cur[tid]; i < fin[tid]; ++i) cols[cbase + i] = N; // sentinel pad
}

// t handles one bf16x2 dword (2 dims). xs = dis*emb pre-scaled; row N zeroed.
__global__ void init_kernel(const float* __restrict__ ue, const float* __restrict__ ie,
                            const float* __restrict__ dis, unsigned* __restrict__ xs,
                            float2* __restrict__ acc2, int UD2, int ND2) {
    int t = blockIdx.x * blockDim.x + threadIdx.x;
    if (t >= ND2 + 32) return;
    if (t >= ND2) { xs[t] = 0u; return; }    // sentinel zero-row N
    const float* src = (t < UD2) ? ue : ie;
    int tt = (t < UD2) ? t : t - UD2;
    float v0 = src[2 * tt];
    float v1 = src[2 * tt + 1];
    acc2[t] = make_float2(v0, v1);
    float dv = dis[t >> 5];
    xs[t] = pack_bf16x2(dv * v0, dv * v1);
}

// One wave per row. lane = (n8 = lane>>3 neighbor slot, dp = lane&7 uint4 idx).
// One uint4 load covers 8 neighbor rows per instruction; one ds_bpermute per
// octet broadcasts the 8 cols. Rows padded to x8 with sentinel -> no tail code.
__global__ __launch_bounds__(256) void spmm_kernel(
        const int* __restrict__ row_ptr, const int* __restrict__ deg,
        const float* __restrict__ dis, const int* __restrict__ cols,
        const unsigned* __restrict__ xs, unsigned* __restrict__ xs_next,
        float4* __restrict__ acc4, int N, float final_scale) {
    int wid = blockIdx.x * 4 + (threadIdx.x >> 6);
    if (wid >= N) return;
    int lane = threadIdx.x & 63;
    int n8 = lane >> 3;
    int dp = lane & 7;
    int start = row_ptr[wid];
    int cntp = (deg[wid] + 7) & ~7;
    float dr = dis[wid];
    const int* colp = cols + start;
    int vbase = n8 << 2;       // bpermute byte addr component
    int dpo = dp << 2;         // dword offset within row (uint4 = 4 dwords)
    float s0 = 0.f, s1 = 0.f, s2 = 0.f, s3 = 0.f;
    float s4 = 0.f, s5 = 0.f, s6 = 0.f, s7 = 0.f;
    for (int chunk = 0; chunk < cntp; chunk += 64) {
        int cv = colp[chunk + lane];           // over-read OK (slack at end)
        int nq = min(64, cntp - chunk) >> 3;
        for (int q = 0; q < nq; ++q) {
            int co = __builtin_amdgcn_ds_bpermute((q << 5) + vbase, cv);
            const uint4* p = (const uint4*)(xs + (((unsigned)co) << 5) + dpo);
            uint4 v = *p;
            s0 += bflo(v.x); s1 += bfhi(v.x);
            s2 += bflo(v.y); s3 += bfhi(v.y);
            s4 += bflo(v.z); s5 += bfhi(v.z);
            s6 += bflo(v.w); s7 += bfhi(v.w);
        }
    }
#pragma unroll
    for (int m = 8; m < 64; m <<= 1) {
        s0 += __shfl_xor(s0, m); s1 += __shfl_xor(s1, m);
        s2 += __shfl_xor(s2, m); s3 += __shfl_xor(s3, m);
        s4 += __shfl_xor(s4, m); s5 += __shfl_xor(s5, m);
        s6 += __shfl_xor(s6, m); s7 += __shfl_xor(s7, m);
    }
    if (n8 == 0) {
        float x0 = dr * s0, x1 = dr * s1, x2 = dr * s2, x3 = dr * s3;
        float x4 = dr * s4, x5 = dr * s5, x6 = dr * s6, x7 = dr * s7;
        uint4 w;
        w.x = pack_bf16x2(dr * x0, dr * x1);   // xs_next = dr^2 * S
        w.y = pack_bf16x2(dr * x2, dr * x3);
        w.z = pack_bf16x2(dr * x4, dr * x5);
        w.w = pack_bf16x2(dr * x6, dr * x7);
        ((uint4*)xs_next)[(wid << 3) + dp] = w;
        int o = (wid << 4) + (dp << 1);
        float4 a = acc4[o];
        a.x = (a.x + x0) * final_scale;
        a.y = (a.y + x1) * final_scale;
        a.z = (a.z + x2) * final_scale;
        a.w = (a.w + x3) * final_scale;
        acc4[o] = a;
        float4 b2 = acc4[o + 1];
        b2.x = (b2.x + x4) * final_scale;
        b2.y = (b2.y + x5) * final_scale;
        b2.z = (b2.z + x6) * final_scale;
        b2.w = (b2.w + x7) * final_scale;
        acc4[o + 1] = b2;
    }
}

extern "C" void kernel_launch(void* const* d_in, const int* in_sizes, int n_in,
                              void* d_out, int out_size, void* d_ws, size_t ws_size,
                              hipStream_t stream) {
    const float* ue = (const float*)d_in[0];
    const float* ie = (const float*)d_in[1];
    const int* eu = (const int*)d_in[2];
    const int* ei = (const int*)d_in[3];
    const int U = in_sizes[0] / D; // 100001
    const int I = in_sizes[1] / D; // 50001
    const int N = U + I;           // 150002
    const int E = in_sizes[2];     // 4,000,000
    const int twoE = 2 * E;
    const int KB = (N + BROWS - 1) / BROWS; // 293
    float* out = (float*)d_out;

    char* ws = (char*)d_ws;
    auto alloc = [&](size_t bytes) {
        char* p = ws;
        ws += (bytes + 255) & ~(size_t)255;
        return p;
    };
    int* deg = (int*)alloc((size_t)N * 4);
    int* row_ptr = (int*)alloc((size_t)N * 4);
    float* dis = (float*)alloc((size_t)N * 4);
    int* bcnt = (int*)alloc(KP * 4);
    int* bbase = (int*)alloc((KP + 1) * 4);
    int* bcursor = (int*)alloc(KP * 4);
    int* cols = (int*)alloc(((size_t)twoE + (size_t)PADSLACK * (KB + 1) + 256) * 4);
    unsigned* pairs = (unsigned*)alloc((size_t)twoE * 4);
    unsigned* xsA = (unsigned*)alloc(((size_t)N + 1) * 32 * 4); // bf16x2, +sentinel row
    unsigned* xsB = (unsigned*)alloc(((size_t)N + 1) * 32 * 4);

    hipMemsetAsync(bcnt, 0, KP * 4, stream);
    bucket_count<<<1024, 256, 0, stream>>>(eu, ei, bcnt, E, U, twoE);
    bscan<<<1, KP, 0, stream>>>(bcnt, bbase, bcursor, KB, twoE);
    bucket_scatter<<<(twoE + TILE - 1) / TILE, 256, 0, stream>>>(
        eu, ei, bcursor, pairs, E, U, twoE);
    csr_build<<<KB, 512, 0, stream>>>(pairs, bbase, deg, row_ptr, dis, cols, N);

    int ND2 = N * 32, UD2 = U * 32;
    init_kernel<<<(ND2 + 32 + 255) / 256, 256, 0, stream>>>(
        ue, ie, dis, xsA, (float2*)out, UD2, ND2);

    unsigned* x = xsA;
    unsigned* xn = xsB;
    for (int l = 0; l < 3; ++l) {
        float fs = (l == 2) ? 0.25f : 1.0f;
        spmm_kernel<<<(N + 3) / 4, 256, 0, stream>>>(
            row_ptr, deg, dis, cols, x, xn, (float4*)out, N, fs);
        unsigned* tmp = x; x = xn; xn = tmp;
    }
}